// Round 2
// baseline (933.851 us; speedup 1.0000x reference)
//
#include <hip/hip_runtime.h>

#define NUM_BASIS 67  // GRID_SIZE + K = 64 + 3

// Interior knots: knots[i] = (i-35)/32 for i in [3,67]; clamped to -1 / +1
// outside. Exact in float32 -> comparisons match the reference's indicators.
__device__ __forceinline__ float kv(int i) {
    i = min(max(i, 3), 67);
    return (float)(i - 35) * 0.03125f;
}

// Compute the knot interval m (knots[m] <= x < knots[m+1], m in [3,66]) and
// the 4 nonzero cubic basis values N[0..3] = B_{m-3..m,3}(x).
// For x outside [-1,1) (or NaN): m set so no column selects, N zeroed --
// matching the reference's all-zero row.
__device__ __forceinline__ void row_basis(float xv, int& m, float N[4]) {
    N[0] = N[1] = N[2] = N[3] = 0.0f;
    m = 1 << 20;  // window [m-3, m] misses every col in [0,66]
    if (xv >= -1.0f && xv < 1.0f) {
        int cell = (int)floorf((xv + 1.0f) * 32.0f);
        cell = min(max(cell, 0), 63);
        m = cell + 3;
        // Fix-up against exact knot values ((x+1)*32 rounding at boundaries).
        while (m > 3 && xv < kv(m)) --m;
        while (m < 66 && xv >= kv(m + 1)) ++m;

        float left[4], right[4];
        N[0] = 1.0f;
#pragma unroll
        for (int d = 1; d <= 3; ++d) {
            left[d] = xv - kv(m + 1 - d);
            right[d] = kv(m + d) - xv;
            float saved = 0.0f;
#pragma unroll
            for (int r = 0; r < d; ++r) {
                float temp = __fdividef(N[r], right[r + 1] + left[d - r]);
                N[r] = saved + right[r + 1] * temp;
                saved = left[d - r] * temp;
            }
            N[d] = saved;
        }
    }
}

__device__ __forceinline__ float sel(int c, int m, const float N[4]) {
    const int d = c - (m - 3);
    float v = 0.0f;
    v = (d == 0) ? N[0] : v;
    v = (d == 1) ? N[1] : v;
    v = (d == 2) ? N[2] : v;
    v = (d == 3) ? N[3] : v;
    return v;
}

// One thread per output float4; pure streaming stores, no LDS, no barriers.
__global__ __launch_bounds__(256) void SplineBasis_kernel(const float* __restrict__ x,
                                                          float4* __restrict__ out4,
                                                          int n4, int out_size, int B) {
    const int g4 = blockIdx.x * 256 + threadIdx.x;
    if (g4 < n4) {
        const int g = g4 * 4;            // out_size < 2^31, safe in int
        const int row0 = g / NUM_BASIS;  // magic-mul
        const int col0 = g - row0 * NUM_BASIS;

        int m0;
        float N0[4];
        row_basis(x[row0], m0, N0);

        int m1 = 1 << 20;
        float N1[4] = {0.f, 0.f, 0.f, 0.f};
        if (col0 > NUM_BASIS - 4 && row0 + 1 < B) {  // float4 spans two rows
            row_basis(x[row0 + 1], m1, N1);
        }

        float4 v;
        int c;
        c = col0 + 0; v.x = (c < NUM_BASIS) ? sel(c, m0, N0) : sel(c - NUM_BASIS, m1, N1);
        c = col0 + 1; v.y = (c < NUM_BASIS) ? sel(c, m0, N0) : sel(c - NUM_BASIS, m1, N1);
        c = col0 + 2; v.z = (c < NUM_BASIS) ? sel(c, m0, N0) : sel(c - NUM_BASIS, m1, N1);
        c = col0 + 3; v.w = (c < NUM_BASIS) ? sel(c, m0, N0) : sel(c - NUM_BASIS, m1, N1);
        out4[g4] = v;
    } else if (g4 == n4) {
        // Scalar tail if out_size % 4 != 0 (not hit for B=2e6: 134e6 % 4 == 0).
        float* out = (float*)out4;
        for (int g = n4 * 4; g < out_size; ++g) {
            const int row = g / NUM_BASIS;
            const int col = g - row * NUM_BASIS;
            int m;
            float N[4];
            row_basis(x[row], m, N);
            out[g] = sel(col, m, N);
        }
    }
}

extern "C" void kernel_launch(void* const* d_in, const int* in_sizes, int n_in,
                              void* d_out, int out_size, void* d_ws, size_t ws_size,
                              hipStream_t stream) {
    const float* x = (const float*)d_in[0];
    const int B = in_sizes[0];
    const int n4 = out_size / 4;
    const int nthreads = n4 + ((out_size & 3) ? 1 : 0);
    const int nblocks = (nthreads + 255) / 256;
    SplineBasis_kernel<<<nblocks, 256, 0, stream>>>(x, (float4*)d_out, n4, out_size, B);
}

// Round 3
// 533.300 us; speedup vs baseline: 1.7511x; 1.7511x over previous
//
#include <hip/hip_runtime.h>

#define NUM_BASIS 67                               // GRID_SIZE + K = 64 + 3
#define ROWS_PER_BLOCK 128
#define TILE_FLOATS (ROWS_PER_BLOCK * NUM_BASIS)   // 8576 floats = 34304 B (16B-aligned tiles)
#define TILE_VEC4 (TILE_FLOATS / 4)                // 2144

// Interior knots: knots[i] = (i-35)/32 for i in [3,67]; clamped to -1 / +1
// outside. Exact in float32 -> comparisons match the reference's indicators.
__device__ __forceinline__ float kv(int i) {
    i = min(max(i, 3), 67);
    return (float)(i - 35) * 0.03125f;
}

// Knot interval m (knots[m] <= x < knots[m+1], m in [3,66]) and the 4 nonzero
// cubic basis values N[0..3] = B_{m-3..m,3}(x). For x outside [-1,1) or NaN:
// m parked far away and N=0 -> all-zero row, matching the reference.
__device__ __forceinline__ void row_basis(float xv, int& m, float N[4]) {
    N[0] = N[1] = N[2] = N[3] = 0.0f;
    m = 1 << 20;
    if (xv >= -1.0f && xv < 1.0f) {
        int cell = (int)floorf((xv + 1.0f) * 32.0f);
        cell = min(max(cell, 0), 63);
        m = cell + 3;
        // Fix-up against exact knot values ((x+1)*32 rounding at boundaries).
        while (m > 3 && xv < kv(m)) --m;
        while (m < 66 && xv >= kv(m + 1)) ++m;

        float left[4], right[4];
        N[0] = 1.0f;
#pragma unroll
        for (int d = 1; d <= 3; ++d) {
            left[d] = xv - kv(m + 1 - d);
            right[d] = kv(m + d) - xv;
            float saved = 0.0f;
#pragma unroll
            for (int r = 0; r < d; ++r) {
                float temp = N[r] / (right[r + 1] + left[d - r]);
                N[r] = saved + right[r + 1] * temp;
                saved = left[d - r] * temp;
            }
            N[d] = saved;
        }
    }
}

__device__ __forceinline__ float pick(int d, float4 n) {
    float v = 0.0f;
    v = (d == 0) ? n.x : v;
    v = (d == 1) ? n.y : v;
    v = (d == 2) ? n.z : v;
    v = (d == 3) ? n.w : v;
    return v;
}

// Phase A: 2M triangles (one per row) into tiny LDS (20 B/row).
// Phase B: register->global fully-coalesced float4 stream with cndmask select.
__global__ __launch_bounds__(256) void SplineBasis_kernel(const float* __restrict__ x,
                                                          float* __restrict__ out,
                                                          int B) {
    __shared__ int s_m[ROWS_PER_BLOCK];
    __shared__ float4 s_N[ROWS_PER_BLOCK];
    const int tid = threadIdx.x;
    const int blockRow0 = blockIdx.x * ROWS_PER_BLOCK;

    if (tid < ROWS_PER_BLOCK) {
        int m = 1 << 20;
        float N[4] = {0.f, 0.f, 0.f, 0.f};
        const int row = blockRow0 + tid;
        if (row < B) row_basis(x[row], m, N);
        s_m[tid] = m;
        s_N[tid] = make_float4(N[0], N[1], N[2], N[3]);
    }
    __syncthreads();

    const int rows = min(ROWS_PER_BLOCK, B - blockRow0);
    if (rows == ROWS_PER_BLOCK) {
        // Tile is self-contained: float4 i covers rows g/67 and (g+3)/67, both
        // within this block's 128 rows (last float4 ends exactly at row 127).
        float4* o4 = (float4*)(out + (size_t)blockRow0 * NUM_BASIS);
        for (int i = tid; i < TILE_VEC4; i += 256) {
            const int g = i * 4;                         // local float index
            const int r0 = (int)((unsigned)g / NUM_BASIS);  // compiler magic-div
            const int c0 = g - r0 * NUM_BASIS;           // [0, 66]
            const int r1 = min(r0 + 1, ROWS_PER_BLOCK - 1);
            // Branchless: always fetch both candidate rows (avoids the
            // wave-wide divergent slow path that killed round 2).
            const int m0 = s_m[r0];
            const int m1 = s_m[r1];
            const float4 n0 = s_N[r0];
            const float4 n1 = s_N[r1];
            float4 v;
            int c;
            c = c0 + 0; v.x = (c < NUM_BASIS) ? pick(c - m0 + 3, n0) : pick(c - NUM_BASIS - m1 + 3, n1);
            c = c0 + 1; v.y = (c < NUM_BASIS) ? pick(c - m0 + 3, n0) : pick(c - NUM_BASIS - m1 + 3, n1);
            c = c0 + 2; v.z = (c < NUM_BASIS) ? pick(c - m0 + 3, n0) : pick(c - NUM_BASIS - m1 + 3, n1);
            c = c0 + 3; v.w = (c < NUM_BASIS) ? pick(c - m0 + 3, n0) : pick(c - NUM_BASIS - m1 + 3, n1);
            o4[i] = v;
        }
    } else if (rows > 0) {
        // Scalar tail (not hit for B = 2,000,000: 2e6 % 128 == 0).
        const int n = rows * NUM_BASIS;
        float* o = out + (size_t)blockRow0 * NUM_BASIS;
        for (int i = tid; i < n; i += 256) {
            const int r0 = (int)((unsigned)i / NUM_BASIS);
            const int c0 = i - r0 * NUM_BASIS;
            o[i] = pick(c0 - s_m[r0] + 3, s_N[r0]);
        }
    }
}

extern "C" void kernel_launch(void* const* d_in, const int* in_sizes, int n_in,
                              void* d_out, int out_size, void* d_ws, size_t ws_size,
                              hipStream_t stream) {
    const float* x = (const float*)d_in[0];
    float* out = (float*)d_out;
    const int B = in_sizes[0];
    const int nblocks = (B + ROWS_PER_BLOCK - 1) / ROWS_PER_BLOCK;
    SplineBasis_kernel<<<nblocks, 256, 0, stream>>>(x, out, B);
}